// Round 1
// baseline (4048.677 us; speedup 1.0000x reference)
//
#include <hip/hip_runtime.h>
#include <hip/hip_cooperative_groups.h>

namespace cg = cooperative_groups;

#define Sn 128
#define Bn 64
#define Hn 512
#define Vn 100
#define TSn 31   // T-1 steps

#define NB 256
#define NT 1024
#define NWAVES (NB*(NT/64))

__device__ __forceinline__ float fast_tanh(float x) {
    float e = __expf(2.0f * x);
    return 1.0f - 2.0f / (e + 1.0f);
}
__device__ __forceinline__ float fast_sigmoid(float x) {
    return 1.0f / (1.0f + __expf(-x));
}
__device__ __forceinline__ float wave_sum(float v) {
    #pragma unroll
    for (int o = 32; o; o >>= 1) v += __shfl_xor(v, o);
    return v;
}
__device__ __forceinline__ float wave_max(float v) {
    #pragma unroll
    for (int o = 32; o; o >>= 1) v = fmaxf(v, __shfl_xor(v, o));
    return v;
}

__global__ __launch_bounds__(NT) void bahdanau_decoder(
    const float* __restrict__ enc, const float* __restrict__ Wemb,
    const float* __restrict__ Wcomb, const float* __restrict__ bcomb,
    const float* __restrict__ Wih, const float* __restrict__ Whh,
    const float* __restrict__ bih, const float* __restrict__ bhh,
    const float* __restrict__ Wout, const float* __restrict__ bout,
    const float* __restrict__ wvat, const float* __restrict__ bvat,
    const int* __restrict__ tgt, float* __restrict__ out, float* __restrict__ ws)
{
    cg::grid_group grid = cg::this_grid();
    float* hb0    = ws;                      // [B][H]
    float* hb1    = ws + Bn*Hn;              // [B][H]
    float* scores = ws + 2*Bn*Hn;            // [S][B]
    float* xbuf   = scores + Sn*Bn;          // [B][H]
    float* lraw   = xbuf + Bn*Hn;            // [B][V]

    __shared__ __align__(16) float attnw[Sn];
    __shared__ __align__(16) float ctxs[Hn];
    __shared__ __align__(16) float embs[Hn];

    const int tid  = threadIdx.x;
    const int bid  = blockIdx.x;
    const int lane = tid & 63;
    const int wid  = tid >> 6;
    const int gw   = bid*(NT/64) + wid;

    // init h = 0 (ws is poisoned, not zeroed)
    for (int i = bid*NT + tid; i < Bn*Hn; i += NB*NT) hb0[i] = 0.0f;
    const float bv = bvat[0];
    grid.sync();

    for (int t = 0; t < TSn; ++t) {
        const float* h    = (t & 1) ? hb1 : hb0;
        float*       hnew = (t & 1) ? hb0 : hb1;

        // ---- Phase A: scores(h_t) full-grid; logits_raw for step t-1 (uses h_t) ----
        for (int d = gw; d < Sn*Bn; d += NWAVES) {
            const int s = d >> 6, b = d & 63;
            const float4* e4 = (const float4*)(enc + ((size_t)s*Bn + b)*Hn);
            const float4* h4 = (const float4*)(h + (size_t)b*Hn);
            const float4* w4 = (const float4*)wvat;
            float acc = 0.0f;
            #pragma unroll
            for (int m = 0; m < 2; ++m) {
                const int f = lane + 64*m;
                const float4 e = e4[f], hv = h4[f], w = w4[f];
                acc += fast_tanh(e.x+hv.x)*w.x + fast_tanh(e.y+hv.y)*w.y +
                       fast_tanh(e.z+hv.z)*w.z + fast_tanh(e.w+hv.w)*w.w;
            }
            acc = wave_sum(acc);
            if (lane == 0) scores[d] = acc + bv;
        }
        if (t > 0) {
            for (int d = gw; d < Bn*Vn; d += NWAVES) {
                const int b = d & 63, v = d >> 6;
                const float4* w4 = (const float4*)(Wout + (size_t)v*Hn);
                const float4* h4 = (const float4*)(h + (size_t)b*Hn);
                float acc = 0.0f;
                #pragma unroll
                for (int m = 0; m < 2; ++m) {
                    const int f = lane + 64*m;
                    const float4 w = w4[f], hv = h4[f];
                    acc += w.x*hv.x + w.y*hv.y + w.z*hv.z + w.w*hv.w;
                }
                acc = wave_sum(acc);
                if (lane == 0) lraw[b*Vn + v] = acc + bout[v];
            }
        }
        grid.sync();

        // ---- Phase B: block = (b = bid>>2, quarter q = bid&3) ----
        {
            const int b = bid >> 2, q = bid & 3;
            if (wid == 0) {
                const float s0 = scores[lane*Bn + b];
                const float s1 = scores[(lane+64)*Bn + b];
                const float mx = wave_max(fmaxf(s0, s1));
                const float e0 = __expf(s0 - mx), e1 = __expf(s1 - mx);
                const float inv = 1.0f / wave_sum(e0 + e1);
                attnw[lane]    = e0 * inv;
                attnw[lane+64] = e1 * inv;
            }
            __syncthreads();
            const int sym = tgt[t*Bn + b];
            if (tid < Hn) {
                const int o = tid;
                const float* ep = enc + (size_t)b*Hn + o;
                float acc = 0.0f;
                #pragma unroll 4
                for (int s = 0; s < Sn; ++s)
                    acc += attnw[s] * ep[(size_t)s*Bn*Hn];
                ctxs[o] = acc;
                embs[o] = Wemb[(size_t)sym*Hn + o];
            }
            __syncthreads();
            for (int jj = wid; jj < 128; jj += NT/64) {
                const int j = q*128 + jj;
                const float4* wc = (const float4*)(Wcomb + (size_t)j*2*Hn);
                const float4* em = (const float4*)embs;
                const float4* cx = (const float4*)ctxs;
                float acc = 0.0f;
                #pragma unroll
                for (int m = 0; m < 2; ++m) {
                    const int f = lane + 64*m;
                    float4 w = wc[f];
                    const float4 e = em[f];
                    acc += w.x*e.x + w.y*e.y + w.z*e.z + w.w*e.w;
                    w = wc[128+f];
                    const float4 c = cx[f];
                    acc += w.x*c.x + w.y*c.y + w.z*c.z + w.w*c.w;
                }
                acc = wave_sum(acc);
                if (lane == 0) xbuf[(size_t)b*Hn + j] = fmaxf(acc + bcomb[j], 0.0f);
            }
            if (t > 0 && q == 0 && wid == 1) {
                const float l0 = (lane < Vn)    ? lraw[b*Vn + lane]      : -3.0e38f;
                const float l1 = (lane+64 < Vn) ? lraw[b*Vn + lane + 64] : -3.0e38f;
                const float mx = wave_max(fmaxf(l0, l1));
                const float e0 = (lane < Vn)    ? __expf(l0 - mx) : 0.0f;
                const float e1 = (lane+64 < Vn) ? __expf(l1 - mx) : 0.0f;
                const float lse = mx + __logf(wave_sum(e0 + e1));
                float* op = out + ((size_t)b*TSn + (t-1))*Vn;
                if (lane < Vn)    op[lane]    = l0 - lse;
                if (lane+64 < Vn) op[lane+64] = l1 - lse;
            }
        }
        grid.sync();

        // ---- Phase C: fused gi+gh+gates -> h_new (wave per (b,j)) ----
        for (int d = gw; d < Bn*Hn; d += NWAVES) {
            const int b = d & 63, j = d >> 6;
            const float4* x4 = (const float4*)(xbuf + (size_t)b*Hn);
            const float4* h4 = (const float4*)(h + (size_t)b*Hn);
            const float4* wr = (const float4*)(Wih + (size_t)j*Hn);
            const float4* wz = (const float4*)(Wih + (size_t)(Hn + j)*Hn);
            const float4* wn = (const float4*)(Wih + (size_t)(2*Hn + j)*Hn);
            const float4* ur = (const float4*)(Whh + (size_t)j*Hn);
            const float4* uz = (const float4*)(Whh + (size_t)(Hn + j)*Hn);
            const float4* un = (const float4*)(Whh + (size_t)(2*Hn + j)*Hn);
            float ar=0.f, az=0.f, an=0.f, cr=0.f, cz=0.f, cn=0.f;
            #pragma unroll
            for (int m = 0; m < 2; ++m) {
                const int f = lane + 64*m;
                const float4 xv = x4[f], hv = h4[f];
                float4 w;
                w = wr[f]; ar += w.x*xv.x + w.y*xv.y + w.z*xv.z + w.w*xv.w;
                w = wz[f]; az += w.x*xv.x + w.y*xv.y + w.z*xv.z + w.w*xv.w;
                w = wn[f]; an += w.x*xv.x + w.y*xv.y + w.z*xv.z + w.w*xv.w;
                w = ur[f]; cr += w.x*hv.x + w.y*hv.y + w.z*hv.z + w.w*hv.w;
                w = uz[f]; cz += w.x*hv.x + w.y*hv.y + w.z*hv.z + w.w*hv.w;
                w = un[f]; cn += w.x*hv.x + w.y*hv.y + w.z*hv.z + w.w*hv.w;
            }
            ar = wave_sum(ar); az = wave_sum(az); an = wave_sum(an);
            cr = wave_sum(cr); cz = wave_sum(cz); cn = wave_sum(cn);
            if (lane == 0) {
                const float r = fast_sigmoid(ar + bih[j]      + cr + bhh[j]);
                const float z = fast_sigmoid(az + bih[Hn+j]   + cz + bhh[Hn+j]);
                const float n = fast_tanh(an + bih[2*Hn+j] + r*(cn + bhh[2*Hn+j]));
                hnew[(size_t)b*Hn + j] = (1.0f - z)*n + z*h[(size_t)b*Hn + j];
            }
        }
        grid.sync();
    }

    // ---- tail: logits for t = TSn-1 from final h ----
    const float* h = (TSn & 1) ? hb1 : hb0;
    for (int d = gw; d < Bn*Vn; d += NWAVES) {
        const int b = d & 63, v = d >> 6;
        const float4* w4 = (const float4*)(Wout + (size_t)v*Hn);
        const float4* h4 = (const float4*)(h + (size_t)b*Hn);
        float acc = 0.0f;
        #pragma unroll
        for (int m = 0; m < 2; ++m) {
            const int f = lane + 64*m;
            const float4 w = w4[f], hv = h4[f];
            acc += w.x*hv.x + w.y*hv.y + w.z*hv.z + w.w*hv.w;
        }
        acc = wave_sum(acc);
        if (lane == 0) lraw[b*Vn + v] = acc + bout[v];
    }
    grid.sync();
    if (bid < Bn && wid == 0) {
        const int b = bid;
        const float l0 = (lane < Vn)    ? lraw[b*Vn + lane]      : -3.0e38f;
        const float l1 = (lane+64 < Vn) ? lraw[b*Vn + lane + 64] : -3.0e38f;
        const float mx = wave_max(fmaxf(l0, l1));
        const float e0 = (lane < Vn)    ? __expf(l0 - mx) : 0.0f;
        const float e1 = (lane+64 < Vn) ? __expf(l1 - mx) : 0.0f;
        const float lse = mx + __logf(wave_sum(e0 + e1));
        float* op = out + ((size_t)b*TSn + (TSn-1))*Vn;
        if (lane < Vn)    op[lane]    = l0 - lse;
        if (lane+64 < Vn) op[lane+64] = l1 - lse;
    }
}

extern "C" void kernel_launch(void* const* d_in, const int* in_sizes, int n_in,
                              void* d_out, int out_size, void* d_ws, size_t ws_size,
                              hipStream_t stream) {
    const float* enc   = (const float*)d_in[0];
    const float* Wemb  = (const float*)d_in[1];
    const float* Wcomb = (const float*)d_in[2];
    const float* bcomb = (const float*)d_in[3];
    const float* Wih   = (const float*)d_in[4];
    const float* Whh   = (const float*)d_in[5];
    const float* bih   = (const float*)d_in[6];
    const float* bhh   = (const float*)d_in[7];
    const float* Wout  = (const float*)d_in[8];
    const float* bout  = (const float*)d_in[9];
    const float* wvat  = (const float*)d_in[10];
    const float* bvat  = (const float*)d_in[11];
    const int*   tgt   = (const int*)d_in[12];
    float* out = (float*)d_out;
    float* ws  = (float*)d_ws;

    void* args[] = { &enc, &Wemb, &Wcomb, &bcomb, &Wih, &Whh, &bih, &bhh,
                     &Wout, &bout, &wvat, &bvat, &tgt, &out, &ws };
    hipLaunchCooperativeKernel((const void*)bahdanau_decoder,
                               dim3(NB), dim3(NT), args, 0, stream);
}

// Round 2
// 3607.758 us; speedup vs baseline: 1.1222x; 1.1222x over previous
//
#include <hip/hip_runtime.h>
#include <hip/hip_bf16.h>
#include <hip/hip_cooperative_groups.h>

namespace cg = cooperative_groups;

#define Sn 128
#define Bn 64
#define Hn 512
#define Vn 100
#define TSn 31   // T-1 steps
#define NB 256
#define NT 1024
#define NXCD 8

typedef unsigned int   u32;
typedef unsigned short u16;

// ---- ws byte offsets (all 16B aligned) ----
#define OFF_ENC   0ull          // bf16 [S][B][H]   8,388,608 B
#define OFF_WEMB  8388608ull    // bf16 [V][H]        102,400 B
#define OFF_WCOMB 8491008ull    // bf16 [H][2H]     1,048,576 B
#define OFF_WIH   9539584ull    // bf16 [3H][H]     1,572,864 B
#define OFF_WHH   11112448ull   // bf16 [3H][H]     1,572,864 B
#define OFF_WOUT  12685312ull   // bf16 [V][H]        102,400 B
#define OFF_XBF   12787712ull   // bf16 [B][H]         65,536 B
#define OFF_HB0   12853248ull   // f32  [B][H]        131,072 B
#define OFF_HB1   12984320ull   // f32  [B][H]        131,072 B
#define OFF_SC    13115392ull   // f32  [B][S]         32,768 B
#define OFF_LR    13148160ull   // f32  [B][V]         25,600 B

__device__ __forceinline__ float bflo(u32 u){ return __uint_as_float(u << 16); }
__device__ __forceinline__ float bfhi(u32 u){ return __uint_as_float(u & 0xffff0000u); }
__device__ __forceinline__ float bf1(u16 u){ return __uint_as_float(((u32)u) << 16); }
__device__ __forceinline__ u16 f2bf(float f){
    __hip_bfloat16 b = __float2bfloat16(f);
    return *(u16*)&b;
}

__device__ __forceinline__ float fast_tanh(float x){
    float e = __expf(2.0f*x);
    return 1.0f - 2.0f/(e + 1.0f);
}
__device__ __forceinline__ float fast_sigmoid(float x){ return 1.0f/(1.0f + __expf(-x)); }

__device__ __forceinline__ float wave_sum(float v){
#pragma unroll
    for (int o = 32; o; o >>= 1) v += __shfl_xor(v, o);
    return v;
}
__device__ __forceinline__ float wave_max(float v){
#pragma unroll
    for (int o = 32; o; o >>= 1) v = fmaxf(v, __shfl_xor(v, o));
    return v;
}

// bf16 row (uint4 = 8 elems) dot fp32 pair-of-float4
__device__ __forceinline__ float dot8(uint4 w, float4 a, float4 b){
    return bflo(w.x)*a.x + bfhi(w.x)*a.y + bflo(w.y)*a.z + bfhi(w.y)*a.w
         + bflo(w.z)*b.x + bfhi(w.z)*b.y + bflo(w.w)*b.z + bfhi(w.w)*b.w;
}
// bf16 dot bf16
__device__ __forceinline__ float dot8bb(uint4 w, uint4 v){
    return bflo(w.x)*bflo(v.x) + bfhi(w.x)*bfhi(v.x)
         + bflo(w.y)*bflo(v.y) + bfhi(w.y)*bfhi(v.y)
         + bflo(w.z)*bflo(v.z) + bfhi(w.z)*bfhi(v.z)
         + bflo(w.w)*bflo(v.w) + bfhi(w.w)*bfhi(v.w);
}

// ---------------- pre-pass: fp32 -> bf16 ----------------
#define CONV(S,D,N)                                              \
    for (int i = t0; i < (N)/4; i += stride) {                   \
        float4 v = ((const float4*)(S))[i];                      \
        ushort4 o;                                               \
        o.x = f2bf(v.x); o.y = f2bf(v.y);                        \
        o.z = f2bf(v.z); o.w = f2bf(v.w);                        \
        ((ushort4*)(D))[i] = o;                                  \
    }

__global__ __launch_bounds__(256) void conv_bf16(
    const float* __restrict__ enc, const float* __restrict__ Wemb,
    const float* __restrict__ Wcomb, const float* __restrict__ Wih,
    const float* __restrict__ Whh, const float* __restrict__ Wout,
    char* __restrict__ ws)
{
    const int t0 = blockIdx.x*256 + threadIdx.x;
    const int stride = gridDim.x*256;
    u16* de = (u16*)(ws + OFF_ENC);
    u16* dm = (u16*)(ws + OFF_WEMB);
    u16* dc = (u16*)(ws + OFF_WCOMB);
    u16* di = (u16*)(ws + OFF_WIH);
    u16* dh = (u16*)(ws + OFF_WHH);
    u16* doo = (u16*)(ws + OFF_WOUT);
    CONV(enc,  de, Sn*Bn*Hn)
    CONV(Wemb, dm, Vn*Hn)
    CONV(Wcomb,dc, Hn*2*Hn)
    CONV(Wih,  di, 3*Hn*Hn)
    CONV(Whh,  dh, 3*Hn*Hn)
    CONV(Wout, doo, Vn*Hn)
}

// ---------------- main cooperative kernel ----------------
__global__ __launch_bounds__(NT) void bahdanau_decoder(
    const float* __restrict__ bcomb, const float* __restrict__ bih,
    const float* __restrict__ bhh, const float* __restrict__ bout,
    const float* __restrict__ wvat, const float* __restrict__ bvat,
    const int* __restrict__ tgt, float* __restrict__ out, char* __restrict__ ws)
{
    cg::grid_group grid = cg::this_grid();

    const u16* enc_bf   = (const u16*)(ws + OFF_ENC);
    const u16* Wemb_bf  = (const u16*)(ws + OFF_WEMB);
    const u16* Wcomb_bf = (const u16*)(ws + OFF_WCOMB);
    const u16* Wih_bf   = (const u16*)(ws + OFF_WIH);
    const u16* Whh_bf   = (const u16*)(ws + OFF_WHH);
    const u16* Wout_bf  = (const u16*)(ws + OFF_WOUT);
    u16*   x_bf   = (u16*)(ws + OFF_XBF);
    float* hb0    = (float*)(ws + OFF_HB0);
    float* hb1    = (float*)(ws + OFF_HB1);
    float* scores = (float*)(ws + OFF_SC);   // [B][S]
    float* lraw   = (float*)(ws + OFF_LR);   // [B][V]

    __shared__ __align__(16) float attnw[Sn];
    __shared__ __align__(16) float ctxs[Hn];
    __shared__ __align__(16) float embs[Hn];

    const int tid  = threadIdx.x;
    const int bid  = blockIdx.x;
    const int lane = tid & 63;
    const int wid  = tid >> 6;
    const int xcd  = bid & (NXCD-1);        // XCD heuristic: round-robin bid%8
    const int lb   = bid >> 3;              // 0..31 local block on XCD
    const int lw   = lb*16 + wid;           // 0..511 local wave on XCD
    const int jbase = xcd*64;               // phase-C j ownership
    const int bbase = xcd*8;                // phase-A b ownership
    // phase-B block mapping: all 4 quarter-blocks of b live on XCD b>>3
    const int pb_b = bbase + (lb >> 2);
    const int pb_q = lb & 3;

    // init h = 0
    for (int i = bid*NT + tid; i < Bn*Hn; i += NB*NT) hb0[i] = 0.0f;
    const float bv = bvat[0];
    // wvat is loop-invariant: hold in registers
    const float4* wv4 = (const float4*)wvat;
    const float4 Wa = wv4[2*lane], Wb = wv4[2*lane+1];
    grid.sync();

    for (int t = 0; t < TSn; ++t) {
        const float* h    = (t & 1) ? hb1 : hb0;
        float*       hnew = (t & 1) ? hb0 : hb1;

        // ---- Phase A (XCD-local): scores for b in [bbase,bbase+8); logits(t-1) ----
        {
            const int ntask = 1024 + ((t > 0) ? 800 : 0);
            for (int i = lw; i < ntask; i += 512) {
                if (i < 1024) {
                    const int s = i >> 3, b = bbase + (i & 7);
                    const uint4 E = ((const uint4*)(enc_bf + ((size_t)s*Bn + b)*Hn))[lane];
                    const float4* h4 = (const float4*)(h + (size_t)b*Hn);
                    const float4 Ha = h4[2*lane], Hb = h4[2*lane+1];
                    float acc =
                        fast_tanh(bflo(E.x)+Ha.x)*Wa.x + fast_tanh(bfhi(E.x)+Ha.y)*Wa.y +
                        fast_tanh(bflo(E.y)+Ha.z)*Wa.z + fast_tanh(bfhi(E.y)+Ha.w)*Wa.w +
                        fast_tanh(bflo(E.z)+Hb.x)*Wb.x + fast_tanh(bfhi(E.z)+Hb.y)*Wb.y +
                        fast_tanh(bflo(E.w)+Hb.z)*Wb.z + fast_tanh(bfhi(E.w)+Hb.w)*Wb.w;
                    acc = wave_sum(acc);
                    if (lane == 0) scores[b*Sn + s] = acc + bv;
                } else {
                    const int ii = i - 1024;
                    const int v = ii >> 3, b = bbase + (ii & 7);
                    const uint4 Wv = ((const uint4*)(Wout_bf + (size_t)v*Hn))[lane];
                    const float4* h4 = (const float4*)(h + (size_t)b*Hn);
                    const float4 Ha = h4[2*lane], Hb = h4[2*lane+1];
                    float acc = dot8(Wv, Ha, Hb);
                    acc = wave_sum(acc);
                    if (lane == 0) lraw[b*Vn + v] = acc + bout[v];
                }
            }
        }
        grid.sync();

        // ---- Phase B (block = (pb_b, pb_q), XCD-local by b) ----
        {
            const int b = pb_b, q = pb_q;
            if (wid == 0) {
                const float s0 = scores[b*Sn + lane];
                const float s1 = scores[b*Sn + lane + 64];
                const float mx = wave_max(fmaxf(s0, s1));
                const float e0 = __expf(s0 - mx), e1 = __expf(s1 - mx);
                const float inv = 1.0f / wave_sum(e0 + e1);
                attnw[lane]    = e0 * inv;
                attnw[lane+64] = e1 * inv;
            }
            __syncthreads();
            const int sym = tgt[t*Bn + b];
            if (tid < Hn) {
                const int o = tid;
                const u16* ep = enc_bf + (size_t)b*Hn + o;
                float acc = 0.0f;
#pragma unroll 8
                for (int s = 0; s < Sn; ++s)
                    acc += attnw[s] * bf1(ep[(size_t)s*Bn*Hn]);
                ctxs[o] = acc;
            } else {
                const int o = tid - Hn;
                embs[o] = bf1(Wemb_bf[(size_t)sym*Hn + o]);
            }
            __syncthreads();
            {
                const float4* e4 = (const float4*)embs;
                const float4* c4 = (const float4*)ctxs;
                const float4 Ea = e4[2*lane], Eb = e4[2*lane+1];
                const float4 Ca = c4[2*lane], Cb = c4[2*lane+1];
#pragma unroll 2
                for (int jj = wid; jj < 128; jj += 16) {
                    const int j = q*128 + jj;
                    const uint4* row = (const uint4*)(Wcomb_bf + (size_t)j*2*Hn);
                    const uint4 w0 = row[lane];
                    const uint4 w1 = row[64 + lane];
                    float acc = dot8(w0, Ea, Eb) + dot8(w1, Ca, Cb);
                    acc = wave_sum(acc);
                    if (lane == 0)
                        x_bf[(size_t)b*Hn + j] = f2bf(fmaxf(acc + bcomb[j], 0.0f));
                }
            }
            if (t > 0 && q == 0 && wid == 1) {
                const float l0 = (lane < Vn)    ? lraw[b*Vn + lane]      : -3.0e38f;
                const float l1 = (lane+64 < Vn) ? lraw[b*Vn + lane + 64] : -3.0e38f;
                const float mx = wave_max(fmaxf(l0, l1));
                const float e0 = (lane < Vn)    ? __expf(l0 - mx) : 0.0f;
                const float e1 = (lane+64 < Vn) ? __expf(l1 - mx) : 0.0f;
                const float lse = mx + __logf(wave_sum(e0 + e1));
                float* op = out + ((size_t)b*TSn + (t-1))*Vn;
                if (lane < Vn)    op[lane]    = l0 - lse;
                if (lane+64 < Vn) op[lane+64] = l1 - lse;
            }
        }
        grid.sync();

        // ---- Phase C (XCD-local by j): GRU gates -> h_new ----
#pragma unroll 2
        for (int rep = 0; rep < 8; ++rep) {
            const int i = lw + rep*512;
            const int j = jbase + (i >> 6);
            const int b = i & 63;
            const uint4 Wr = ((const uint4*)(Wih_bf + (size_t)j*Hn))[lane];
            const uint4 Wz = ((const uint4*)(Wih_bf + (size_t)(Hn + j)*Hn))[lane];
            const uint4 Wn = ((const uint4*)(Wih_bf + (size_t)(2*Hn + j)*Hn))[lane];
            const uint4 Ur = ((const uint4*)(Whh_bf + (size_t)j*Hn))[lane];
            const uint4 Uz = ((const uint4*)(Whh_bf + (size_t)(Hn + j)*Hn))[lane];
            const uint4 Un = ((const uint4*)(Whh_bf + (size_t)(2*Hn + j)*Hn))[lane];
            const uint4 Xv = ((const uint4*)(x_bf + (size_t)b*Hn))[lane];
            const float4* h4 = (const float4*)(h + (size_t)b*Hn);
            const float4 Ha = h4[2*lane], Hb = h4[2*lane+1];
            float ar = dot8bb(Wr, Xv), az = dot8bb(Wz, Xv), an = dot8bb(Wn, Xv);
            float cr = dot8(Ur, Ha, Hb), cz = dot8(Uz, Ha, Hb), cn = dot8(Un, Ha, Hb);
            ar = wave_sum(ar); az = wave_sum(az); an = wave_sum(an);
            cr = wave_sum(cr); cz = wave_sum(cz); cn = wave_sum(cn);
            if (lane == 0) {
                const float r = fast_sigmoid(ar + bih[j]      + cr + bhh[j]);
                const float z = fast_sigmoid(az + bih[Hn+j]   + cz + bhh[Hn+j]);
                const float n = fast_tanh(an + bih[2*Hn+j] + r*(cn + bhh[2*Hn+j]));
                hnew[(size_t)b*Hn + j] = (1.0f - z)*n + z*h[(size_t)b*Hn + j];
            }
        }
        grid.sync();
    }

    // ---- tail: logits for t = TSn-1 from final h ----
    const float* h = (TSn & 1) ? hb1 : hb0;
    for (int i = lw; i < 800; i += 512) {
        const int v = i >> 3, b = bbase + (i & 7);
        const uint4 Wv = ((const uint4*)(Wout_bf + (size_t)v*Hn))[lane];
        const float4* h4 = (const float4*)(h + (size_t)b*Hn);
        const float4 Ha = h4[2*lane], Hb = h4[2*lane+1];
        float acc = dot8(Wv, Ha, Hb);
        acc = wave_sum(acc);
        if (lane == 0) lraw[b*Vn + v] = acc + bout[v];
    }
    grid.sync();
    if (bid < Bn && wid == 0) {
        const int b = bid;
        const float l0 = (lane < Vn)    ? lraw[b*Vn + lane]      : -3.0e38f;
        const float l1 = (lane+64 < Vn) ? lraw[b*Vn + lane + 64] : -3.0e38f;
        const float mx = wave_max(fmaxf(l0, l1));
        const float e0 = (lane < Vn)    ? __expf(l0 - mx) : 0.0f;
        const float e1 = (lane+64 < Vn) ? __expf(l1 - mx) : 0.0f;
        const float lse = mx + __logf(wave_sum(e0 + e1));
        float* op = out + ((size_t)b*TSn + (TSn-1))*Vn;
        if (lane < Vn)    op[lane]    = l0 - lse;
        if (lane+64 < Vn) op[lane+64] = l1 - lse;
    }
}

extern "C" void kernel_launch(void* const* d_in, const int* in_sizes, int n_in,
                              void* d_out, int out_size, void* d_ws, size_t ws_size,
                              hipStream_t stream) {
    const float* enc   = (const float*)d_in[0];
    const float* Wemb  = (const float*)d_in[1];
    const float* Wcomb = (const float*)d_in[2];
    const float* bcomb = (const float*)d_in[3];
    const float* Wih   = (const float*)d_in[4];
    const float* Whh   = (const float*)d_in[5];
    const float* bih   = (const float*)d_in[6];
    const float* bhh   = (const float*)d_in[7];
    const float* Wout  = (const float*)d_in[8];
    const float* bout  = (const float*)d_in[9];
    const float* wvat  = (const float*)d_in[10];
    const float* bvat  = (const float*)d_in[11];
    const int*   tgt   = (const int*)d_in[12];
    float* out = (float*)d_out;
    char*  ws  = (char*)d_ws;

    conv_bf16<<<1024, 256, 0, stream>>>(enc, Wemb, Wcomb, Wih, Whh, Wout, ws);

    void* args[] = { &bcomb, &bih, &bhh, &bout, &wvat, &bvat, &tgt, &out, &ws };
    hipLaunchCooperativeKernel((const void*)bahdanau_decoder,
                               dim3(NB), dim3(NT), args, 0, stream);
}

// Round 3
// 2744.734 us; speedup vs baseline: 1.4751x; 1.3144x over previous
//
#include <hip/hip_runtime.h>
#include <hip/hip_fp16.h>

#define Sn 128
#define Bn 64
#define Hn 512
#define Vn 100
#define TSn 31   // T-1 steps

typedef unsigned int   u32;
typedef unsigned short u16;
typedef _Float16 f16x2 __attribute__((ext_vector_type(2)));

// ---- ws byte offsets (all 16B aligned), all arrays stored as fp16 ----
#define OFF_ENC   0ull          // [S][B][H]   8,388,608 B
#define OFF_WEMB  8388608ull    // [V][H]        102,400 B
#define OFF_WCOMB 8491008ull    // [H][2H]     1,048,576 B
#define OFF_WIH   9539584ull    // [3H][H]     1,572,864 B
#define OFF_WHH   11112448ull   // [3H][H]     1,572,864 B
#define OFF_WOUT  12685312ull   // [V][H]        102,400 B

__device__ __forceinline__ u16 f2h(float f){ _Float16 h=(_Float16)f; return __builtin_bit_cast(u16,h); }
__device__ __forceinline__ f16x2 uh2(u32 u){ return __builtin_bit_cast(f16x2,u); }
__device__ __forceinline__ float2 h2f(u32 u){ f16x2 h=uh2(u); return make_float2((float)h.x,(float)h.y); }

#if __has_builtin(__builtin_amdgcn_fdot2)
__device__ __forceinline__ float dot2acc(u32 a, u32 b, float acc){
    return __builtin_amdgcn_fdot2(uh2(a), uh2(b), acc, false);
}
#else
__device__ __forceinline__ float dot2acc(u32 a, u32 b, float acc){
    float2 x=h2f(a), y=h2f(b); return acc + x.x*y.x + x.y*y.y;
}
#endif

__device__ __forceinline__ float dot8h(uint4 w, uint4 v, float acc){
    acc = dot2acc(w.x, v.x, acc); acc = dot2acc(w.y, v.y, acc);
    acc = dot2acc(w.z, v.z, acc); acc = dot2acc(w.w, v.w, acc);
    return acc;
}

__device__ __forceinline__ float fast_tanh(float x){
    float e = __expf(2.0f*x);
    return 1.0f - 2.0f/(e + 1.0f);
}
__device__ __forceinline__ float fast_sigmoid(float x){ return 1.0f/(1.0f + __expf(-x)); }

__device__ __forceinline__ float wave_sum(float v){
#pragma unroll
    for (int o = 32; o; o >>= 1) v += __shfl_xor(v, o);
    return v;
}
__device__ __forceinline__ float wave_max(float v){
#pragma unroll
    for (int o = 32; o; o >>= 1) v = fmaxf(v, __shfl_xor(v, o));
    return v;
}

// ---------------- pre-pass: fp32 -> fp16 ----------------
#define CONV(S,D,N)                                              \
    for (int i = t0; i < (N)/4; i += stride) {                   \
        float4 v = ((const float4*)(S))[i];                      \
        ushort4 o;                                               \
        o.x = f2h(v.x); o.y = f2h(v.y);                          \
        o.z = f2h(v.z); o.w = f2h(v.w);                          \
        ((ushort4*)(D))[i] = o;                                  \
    }

__global__ __launch_bounds__(256) void conv_f16(
    const float* __restrict__ enc, const float* __restrict__ Wemb,
    const float* __restrict__ Wcomb, const float* __restrict__ Wih,
    const float* __restrict__ Whh, const float* __restrict__ Wout,
    char* __restrict__ ws)
{
    const int t0 = blockIdx.x*256 + threadIdx.x;
    const int stride = gridDim.x*256;
    u16* de = (u16*)(ws + OFF_ENC);
    u16* dm = (u16*)(ws + OFF_WEMB);
    u16* dc = (u16*)(ws + OFF_WCOMB);
    u16* di = (u16*)(ws + OFF_WIH);
    u16* dh = (u16*)(ws + OFF_WHH);
    u16* doo = (u16*)(ws + OFF_WOUT);
    CONV(enc,  de, Sn*Bn*Hn)
    CONV(Wemb, dm, Vn*Hn)
    CONV(Wcomb,dc, Hn*2*Hn)
    CONV(Wih,  di, 3*Hn*Hn)
    CONV(Whh,  dh, 3*Hn*Hn)
    CONV(Wout, doo, Vn*Hn)
}

// ---------------- main kernel: one block per batch element, NO grid syncs ----------------
__global__ __launch_bounds__(1024) void bahdanau_decoder(
    const float* __restrict__ bcomb, const float* __restrict__ bih,
    const float* __restrict__ bhh, const float* __restrict__ bout,
    const float* __restrict__ wvat, const float* __restrict__ bvat,
    const int* __restrict__ tgt, float* __restrict__ out, const char* __restrict__ ws)
{
    const u16* enc_h   = (const u16*)(ws + OFF_ENC);
    const u16* Wemb_h  = (const u16*)(ws + OFF_WEMB);
    const u16* Wcomb_h = (const u16*)(ws + OFF_WCOMB);
    const u16* Wih_h   = (const u16*)(ws + OFF_WIH);
    const u16* Whh_h   = (const u16*)(ws + OFF_WHH);
    const u16* Wout_h  = (const u16*)(ws + OFF_WOUT);

    __shared__ __align__(16) float h_s[2][Hn];     // fp32 master recurrent state
    __shared__ __align__(16) u16   hh_s[2][Hn];    // fp16 packed copy for dots
    __shared__ __align__(16) u16   ec_s[2*Hn];     // [emb ; ctx] packed fp16
    __shared__ __align__(16) u16   x_s[Hn];        // x packed fp16
    __shared__ __align__(16) float scores_s[Sn];
    __shared__ __align__(16) float attnw_s[Sn];
    __shared__ __align__(16) float lraw_s[128];

    const int tid  = threadIdx.x;
    const int lane = tid & 63;
    const int wid  = tid >> 6;
    const int b    = blockIdx.x;

    if (tid < Hn) { h_s[0][tid] = 0.0f; hh_s[0][tid] = 0; }
    // loop-invariant vat weights in registers (lane's 8-elem slice)
    const float4 Wa = ((const float4*)wvat)[2*lane];
    const float4 Wb = ((const float4*)wvat)[2*lane+1];
    const float bv = bvat[0];
    __syncthreads();

    for (int t = 0; t < TSn; ++t) {
        const int cur = t & 1, nxt = cur ^ 1;

        // P1: scores[s] = tanh(enc[s,b,:]+h)·wvat + bv   (wave per s)
        for (int s = wid; s < Sn; s += 16) {
            const uint4 E = ((const uint4*)(enc_h + ((size_t)s*Bn + b)*Hn))[lane];
            const float4 Ha = ((const float4*)h_s[cur])[2*lane];
            const float4 Hb = ((const float4*)h_s[cur])[2*lane+1];
            const float2 e0 = h2f(E.x), e1 = h2f(E.y), e2 = h2f(E.z), e3 = h2f(E.w);
            float acc = fast_tanh(e0.x+Ha.x)*Wa.x + fast_tanh(e0.y+Ha.y)*Wa.y
                      + fast_tanh(e1.x+Ha.z)*Wa.z + fast_tanh(e1.y+Ha.w)*Wa.w
                      + fast_tanh(e2.x+Hb.x)*Wb.x + fast_tanh(e2.y+Hb.y)*Wb.y
                      + fast_tanh(e3.x+Hb.z)*Wb.z + fast_tanh(e3.y+Hb.w)*Wb.w;
            acc = wave_sum(acc);
            if (lane == 0) scores_s[s] = acc + bv;
        }
        __syncthreads();

        // P2: softmax over S (wave 0) || embedding row copy (waves 8-9)
        if (wid == 0) {
            const float s0 = scores_s[lane], s1 = scores_s[lane+64];
            const float mx = wave_max(fmaxf(s0, s1));
            const float e0 = __expf(s0-mx), e1 = __expf(s1-mx);
            const float inv = 1.0f / wave_sum(e0 + e1);
            attnw_s[lane]    = e0 * inv;
            attnw_s[lane+64] = e1 * inv;
        } else if (wid == 8 || wid == 9) {
            const int sym = tgt[t*Bn + b];
            const int i = tid - 512;           // 0..127 uint4 chunks of 512 f16
            ((uint4*)ec_s)[i] = ((const uint4*)(Wemb_h + (size_t)sym*Hn))[i];
        }
        __syncthreads();

        // P3: ctx[o] = sum_s attnw[s]*enc[s,b,o]   (thread per o, 2 accumulators)
        if (tid < Hn) {
            const u16* ep = enc_h + (size_t)b*Hn + tid;
            float a0 = 0.0f, a1 = 0.0f;
#pragma unroll 8
            for (int s = 0; s < Sn; s += 2) {
                a0 += attnw_s[s]   * (float)(*(const _Float16*)(ep + (size_t)s    *Bn*Hn));
                a1 += attnw_s[s+1] * (float)(*(const _Float16*)(ep + (size_t)(s+1)*Bn*Hn));
            }
            ec_s[Hn + tid] = f2h(a0 + a1);
        }
        __syncthreads();

        // P4: x[j] = relu(Wcomb[j,:]·[emb;ctx] + bcomb[j])   (wave per j)
        for (int j = wid; j < Hn; j += 16) {
            const uint4* row = (const uint4*)(Wcomb_h + (size_t)j*2*Hn);
            const uint4 w0 = row[lane], w1 = row[64+lane];
            const uint4 e0 = ((const uint4*)ec_s)[lane], e1 = ((const uint4*)ec_s)[64+lane];
            float acc = dot8h(w1, e1, dot8h(w0, e0, 0.0f));
            acc = wave_sum(acc);
            if (lane == 0) x_s[j] = f2h(fmaxf(acc + bcomb[j], 0.0f));
        }
        __syncthreads();

        // P5: GRU gates -> h_new   (wave per j; r,z fold x-side+h-side before reduce)
        for (int j = wid; j < Hn; j += 16) {
            const uint4 Wr = ((const uint4*)(Wih_h + (size_t)j*Hn))[lane];
            const uint4 Wz = ((const uint4*)(Wih_h + (size_t)(Hn + j)*Hn))[lane];
            const uint4 Wn = ((const uint4*)(Wih_h + (size_t)(2*Hn + j)*Hn))[lane];
            const uint4 Ur = ((const uint4*)(Whh_h + (size_t)j*Hn))[lane];
            const uint4 Uz = ((const uint4*)(Whh_h + (size_t)(Hn + j)*Hn))[lane];
            const uint4 Un = ((const uint4*)(Whh_h + (size_t)(2*Hn + j)*Hn))[lane];
            const uint4 Xv = ((const uint4*)x_s)[lane];
            const uint4 Hv = ((const uint4*)hh_s[cur])[lane];
            float gr = dot8h(Ur, Hv, dot8h(Wr, Xv, 0.0f));
            float gz = dot8h(Uz, Hv, dot8h(Wz, Xv, 0.0f));
            float an = dot8h(Wn, Xv, 0.0f);
            float cn = dot8h(Un, Hv, 0.0f);
            gr = wave_sum(gr); gz = wave_sum(gz);
            an = wave_sum(an); cn = wave_sum(cn);
            const float r = fast_sigmoid(gr + bih[j]      + bhh[j]);
            const float z = fast_sigmoid(gz + bih[Hn+j]   + bhh[Hn+j]);
            const float n = fast_tanh(an + bih[2*Hn+j] + r*(cn + bhh[2*Hn+j]));
            const float hv = (1.0f - z)*n + z*h_s[cur][j];
            if (lane == 0) { h_s[nxt][j] = hv; hh_s[nxt][j] = f2h(hv); }
        }
        __syncthreads();

        // P6: raw logits from h_new   (wave per v)
        for (int v = wid; v < Vn; v += 16) {
            const uint4 Wv = ((const uint4*)(Wout_h + (size_t)v*Hn))[lane];
            const uint4 Hv = ((const uint4*)hh_s[nxt])[lane];
            float acc = dot8h(Wv, Hv, 0.0f);
            acc = wave_sum(acc);
            if (lane == 0) lraw_s[v] = acc + bout[v];
        }
        __syncthreads();

        // P7: log-softmax + store (wave 0; other waves proceed to next step's P1)
        if (wid == 0) {
            const float l0 = (lane < Vn)    ? lraw_s[lane]      : -3.0e38f;
            const float l1 = (lane+64 < Vn) ? lraw_s[lane+64]   : -3.0e38f;
            const float mx = wave_max(fmaxf(l0, l1));
            const float e0 = (lane < Vn)    ? __expf(l0-mx) : 0.0f;
            const float e1 = (lane+64 < Vn) ? __expf(l1-mx) : 0.0f;
            const float lse = mx + __logf(wave_sum(e0 + e1));
            float* op = out + ((size_t)b*TSn + t)*Vn;
            if (lane < Vn)    op[lane]    = l0 - lse;
            if (lane+64 < Vn) op[lane+64] = l1 - lse;
        }
        // no barrier needed: wave0 finishes P7 before anyone passes next sync1;
        // lraw_s is next written only after next step's sync5.
    }
}

extern "C" void kernel_launch(void* const* d_in, const int* in_sizes, int n_in,
                              void* d_out, int out_size, void* d_ws, size_t ws_size,
                              hipStream_t stream) {
    const float* enc   = (const float*)d_in[0];
    const float* Wemb  = (const float*)d_in[1];
    const float* Wcomb = (const float*)d_in[2];
    const float* bcomb = (const float*)d_in[3];
    const float* Wih   = (const float*)d_in[4];
    const float* Whh   = (const float*)d_in[5];
    const float* bih   = (const float*)d_in[6];
    const float* bhh   = (const float*)d_in[7];
    const float* Wout  = (const float*)d_in[8];
    const float* bout  = (const float*)d_in[9];
    const float* wvat  = (const float*)d_in[10];
    const float* bvat  = (const float*)d_in[11];
    const int*   tgt   = (const int*)d_in[12];
    float* out = (float*)d_out;
    char*  ws  = (char*)d_ws;

    conv_f16<<<1024, 256, 0, stream>>>(enc, Wemb, Wcomb, Wih, Whh, Wout, ws);

    bahdanau_decoder<<<dim3(Bn), dim3(1024), 0, stream>>>(
        bcomb, bih, bhh, bout, wvat, bvat, tgt, out, ws);
}

// Round 4
// 1217.793 us; speedup vs baseline: 3.3246x; 2.2539x over previous
//
#include <hip/hip_runtime.h>
#include <hip/hip_fp16.h>

#define Sn 128
#define Bn 64
#define Hn 512
#define Vn 100
#define TSn 31   // T-1 steps

typedef unsigned int   u32;
typedef unsigned short u16;
typedef _Float16 f16x2 __attribute__((ext_vector_type(2)));

// ---- ws byte offsets (16B aligned) ----
#define OFF_ENC2  0ull          // fp16 [B][S][H] (transposed)  8,388,608
#define OFF_WEMB  8388608ull    // fp16 [V][H]
#define OFF_WCOMB 8491008ull    // fp16 [H][2H]
#define OFF_WIH   9539584ull    // fp16 [3H][H]
#define OFF_WHH   11112448ull   // fp16 [3H][H]
#define OFF_WOUT  12685312ull   // fp16 [V][H]
#define OFF_XEX   12787712ull   // fp16 [B][H]      x exchange
#define OFF_HEX   12853248ull   // f32  [B][H]      h exchange
#define OFF_HHEX  12984320ull   // fp16 [B][H]      h fp16 exchange
#define OFF_PLOG  13049856ull   // f32  [B][4][100] partial logits
#define OFF_CNT   13152256ull   // u32  [2][64]     barrier counters

__device__ __forceinline__ u16 f2h(float f){ _Float16 h=(_Float16)f; return __builtin_bit_cast(u16,h); }
__device__ __forceinline__ f16x2 uh2(u32 u){ return __builtin_bit_cast(f16x2,u); }
__device__ __forceinline__ float2 h2f(u32 u){ f16x2 h=uh2(u); return make_float2((float)h.x,(float)h.y); }
__device__ __forceinline__ u32 pack2h(float a, float b){ return (u32)f2h(a) | ((u32)f2h(b) << 16); }

#if __has_builtin(__builtin_amdgcn_fdot2)
__device__ __forceinline__ float dot2acc(u32 a, u32 b, float acc){
    return __builtin_amdgcn_fdot2(uh2(a), uh2(b), acc, false);
}
#else
__device__ __forceinline__ float dot2acc(u32 a, u32 b, float acc){
    float2 x=h2f(a), y=h2f(b); return acc + x.x*y.x + x.y*y.y;
}
#endif

__device__ __forceinline__ float dot8h(uint4 w, uint4 v, float acc){
    acc = dot2acc(w.x, v.x, acc); acc = dot2acc(w.y, v.y, acc);
    acc = dot2acc(w.z, v.z, acc); acc = dot2acc(w.w, v.w, acc);
    return acc;
}

__device__ __forceinline__ float fast_tanh(float x){
    float e = __expf(2.0f*x);
    return 1.0f - 2.0f/(e + 1.0f);
}
__device__ __forceinline__ float fast_sigmoid(float x){ return 1.0f/(1.0f + __expf(-x)); }

__device__ __forceinline__ float wave_sum(float v){
#pragma unroll
    for (int o = 32; o; o >>= 1) v += __shfl_xor(v, o);
    return v;
}
__device__ __forceinline__ float wave_max(float v){
#pragma unroll
    for (int o = 32; o; o >>= 1) v = fmaxf(v, __shfl_xor(v, o));
    return v;
}

// 4-sibling barrier: volatile-store data first, then call. Monotonic counter.
__device__ __forceinline__ void sib_barrier(u32* cnt, u32 target){
    asm volatile("s_waitcnt vmcnt(0)" ::: "memory");  // per-wave: drain own volatile stores to LLC
    __syncthreads();                                   // all waves drained
    if (threadIdx.x == 0) {
        __hip_atomic_fetch_add(cnt, 1u, __ATOMIC_RELAXED, __HIP_MEMORY_SCOPE_AGENT);
        u32 v;
        do {
            __builtin_amdgcn_s_sleep(2);
            v = __hip_atomic_load(cnt, __ATOMIC_RELAXED, __HIP_MEMORY_SCOPE_AGENT);
        } while (v < target);
    }
    __syncthreads();
}

// ---------------- pre-pass: fp32 -> fp16 (+ enc transpose, + counter zero) ----------------
#define CONV(S,D,N)                                              \
    for (int i = t0; i < (N)/4; i += stride) {                   \
        float4 v = ((const float4*)(S))[i];                      \
        ushort4 o;                                               \
        o.x = f2h(v.x); o.y = f2h(v.y);                          \
        o.z = f2h(v.z); o.w = f2h(v.w);                          \
        ((ushort4*)(D))[i] = o;                                  \
    }

__global__ __launch_bounds__(256) void conv_f16(
    const float* __restrict__ enc, const float* __restrict__ Wemb,
    const float* __restrict__ Wcomb, const float* __restrict__ Wih,
    const float* __restrict__ Whh, const float* __restrict__ Wout,
    char* __restrict__ ws)
{
    const int t0 = blockIdx.x*256 + threadIdx.x;
    const int stride = gridDim.x*256;
    if (blockIdx.x == 0 && threadIdx.x < 128) ((u32*)(ws + OFF_CNT))[threadIdx.x] = 0;

    // enc [S][B][H] f32 -> [B][S][H] fp16 (output-linear, 4-elem chunks)
    {
        u16* de = (u16*)(ws + OFF_ENC2);
        for (int c = t0; c < Sn*Bn*Hn/4; c += stride) {
            const int h4 = c & 127;          // H/4 = 128
            const int s  = (c >> 7) & 127;
            const int bb = c >> 14;
            float4 v = ((const float4*)enc)[(s*Bn + bb)*(Hn/4) + h4];
            ushort4 o;
            o.x = f2h(v.x); o.y = f2h(v.y); o.z = f2h(v.z); o.w = f2h(v.w);
            ((ushort4*)de)[c] = o;
        }
    }
    u16* dm = (u16*)(ws + OFF_WEMB);
    u16* dc = (u16*)(ws + OFF_WCOMB);
    u16* di = (u16*)(ws + OFF_WIH);
    u16* dh = (u16*)(ws + OFF_WHH);
    u16* doo = (u16*)(ws + OFF_WOUT);
    CONV(Wemb, dm, Vn*Hn)
    CONV(Wcomb,dc, Hn*2*Hn)
    CONV(Wih,  di, 3*Hn*Hn)
    CONV(Whh,  dh, 3*Hn*Hn)
    CONV(Wout, doo, Vn*Hn)
}

// ---------------- main kernel: 4 sibling blocks per batch element ----------------
// bid: xcd=bid&7, lb=bid>>3;  q=xcd&3 (j-quarter, XCD-resident weights), b=2*lb+(xcd>>2)
__global__ __launch_bounds__(1024) void bahdanau_decoder(
    const float* __restrict__ bcomb, const float* __restrict__ bih,
    const float* __restrict__ bhh, const float* __restrict__ bout,
    const float* __restrict__ wvat, const float* __restrict__ bvat,
    const int* __restrict__ tgt, float* __restrict__ out, char* __restrict__ ws)
{
    const u16* Wemb_h  = (const u16*)(ws + OFF_WEMB);
    const u16* Wcomb_h = (const u16*)(ws + OFF_WCOMB);
    const u16* Wih_h   = (const u16*)(ws + OFF_WIH);
    const u16* Whh_h   = (const u16*)(ws + OFF_WHH);
    const u16* Wout_h  = (const u16*)(ws + OFF_WOUT);
    u32* cntA = (u32*)(ws + OFF_CNT);
    u32* cntB = cntA + 64;

    extern __shared__ __align__(16) u16 enc_lds[];   // [S][H] fp16 = 131072 B (dynamic)
    __shared__ __align__(16) float h_full[Hn];       // fp32 master h (full)
    __shared__ __align__(16) u16   hh_full[Hn];      // fp16 h (full)
    __shared__ __align__(16) u16   ec_s[2*Hn];       // [emb ; ctx] fp16
    __shared__ __align__(16) u16   x_s[Hn];          // x fp16 (full, assembled)
    __shared__ __align__(16) float scores_s[Sn];
    __shared__ __align__(16) float attnw_s[Sn];
    __shared__ __align__(16) float2 pctx[4][256];    // ctx partials (4 s-chunks)
    __shared__ __align__(16) float plog_s[112];
    __shared__ __align__(16) u16   hn16_stage[128];

    const int tid  = threadIdx.x;
    const int lane = tid & 63;
    const int wid  = tid >> 6;
    const int bid  = blockIdx.x;
    const int xcd  = bid & 7;
    const int lb   = bid >> 3;
    const int q    = xcd & 3;           // owned j-quarter
    const int b    = 2*lb + (xcd >> 2); // owned batch element
    const int j0   = q*128;

    // fill enc LDS (131072 B = 8192 uint4), resident across all steps
    {
        const uint4* src = (const uint4*)(ws + OFF_ENC2 + (size_t)b*Sn*Hn*2);
        for (int i = tid; i < Sn*Hn/8; i += 1024) ((uint4*)enc_lds)[i] = src[i];
    }
    if (tid < Hn) { h_full[tid] = 0.0f; hh_full[tid] = 0; }
    const float4 Wa = ((const float4*)wvat)[2*lane];
    const float4 Wb = ((const float4*)wvat)[2*lane+1];
    const float bv = bvat[0];
    __syncthreads();

    for (int t = 0; t < TSn; ++t) {
        const u32 tgtc = 4u*(t+1);

        // P1 (replicated): scores[s] = tanh(enc[s]+h)·wvat + bv   (wave per s, from LDS)
        for (int s = wid; s < Sn; s += 16) {
            const uint4 E = ((const uint4*)(enc_lds + s*Hn))[lane];
            const float4 Ha = ((const float4*)h_full)[2*lane];
            const float4 Hb = ((const float4*)h_full)[2*lane+1];
            const float2 e0 = h2f(E.x), e1 = h2f(E.y), e2 = h2f(E.z), e3 = h2f(E.w);
            float acc = fast_tanh(e0.x+Ha.x)*Wa.x + fast_tanh(e0.y+Ha.y)*Wa.y
                      + fast_tanh(e1.x+Ha.z)*Wa.z + fast_tanh(e1.y+Ha.w)*Wa.w
                      + fast_tanh(e2.x+Hb.x)*Wb.x + fast_tanh(e2.y+Hb.y)*Wb.y
                      + fast_tanh(e3.x+Hb.z)*Wb.z + fast_tanh(e3.y+Hb.w)*Wb.w;
            acc = wave_sum(acc);
            if (lane == 0) scores_s[s] = acc + bv;
        }
        __syncthreads();

        // P2 (replicated): softmax (wave 0) || emb row -> ec_s[0:512] (wave 1)
        if (wid == 0) {
            const float s0 = scores_s[lane], s1 = scores_s[lane+64];
            const float mx = wave_max(fmaxf(s0, s1));
            const float e0 = __expf(s0-mx), e1 = __expf(s1-mx);
            const float inv = 1.0f / wave_sum(e0 + e1);
            attnw_s[lane]    = e0 * inv;
            attnw_s[lane+64] = e1 * inv;
        } else if (wid == 1) {
            const int sym = tgt[t*Bn + b];
            ((uint4*)ec_s)[lane] = ((const uint4*)(Wemb_h + (size_t)sym*Hn))[lane];
        }
        __syncthreads();

        // P3 (replicated): ctx from LDS; thread = (o-pair, s-chunk)
        {
            const int op = tid & 255;       // o = 2*op
            const int sc = tid >> 8;        // 4 chunks of 32 s
            float2 acc = make_float2(0.f, 0.f);
#pragma unroll 8
            for (int k = 0; k < 32; ++k) {
                const int s = sc*32 + k;
                const float2 ef = h2f(*(const u32*)(enc_lds + s*Hn + 2*op));
                const float a = attnw_s[s];
                acc.x += a*ef.x; acc.y += a*ef.y;
            }
            pctx[sc][op] = acc;
        }
        __syncthreads();
        if (tid < 256) {
            float2 c0 = pctx[0][tid], c1 = pctx[1][tid], c2 = pctx[2][tid], c3 = pctx[3][tid];
            ((u32*)(ec_s + Hn))[tid] = pack2h(c0.x+c1.x+c2.x+c3.x, c0.y+c1.y+c2.y+c3.y);
        }
        __syncthreads();

        // P4 (split by j): x[j] for owned quarter
        for (int jj = wid; jj < 128; jj += 16) {
            const int j = j0 + jj;
            const uint4* row = (const uint4*)(Wcomb_h + (size_t)j*2*Hn);
            const uint4 w0 = row[lane], w1 = row[64+lane];
            const uint4 e0 = ((const uint4*)ec_s)[lane], e1 = ((const uint4*)ec_s)[64+lane];
            float acc = dot8h(w1, e1, dot8h(w0, e0, 0.0f));
            acc = wave_sum(acc);
            if (lane == 0) x_s[j] = f2h(fmaxf(acc + bcomb[j], 0.0f));
        }
        __syncthreads();
        // exchange x (own 128 fp16 = 64 u32)
        if (wid == 0)
            ((volatile u32*)(ws + OFF_XEX))[b*256 + q*64 + lane] = ((u32*)x_s)[q*64 + lane];
        sib_barrier(cntA + b, tgtc);
        if (wid < 3) {
            const int qq = (q + 1 + wid) & 3;
            ((u32*)x_s)[qq*64 + lane] = ((const volatile u32*)(ws + OFF_XEX))[b*256 + qq*64 + lane];
        }
        __syncthreads();

        // P5 (split by j): GRU gates -> h_new[j-slice]
        for (int jj = wid; jj < 128; jj += 16) {
            const int j = j0 + jj;
            const uint4 Wr = ((const uint4*)(Wih_h + (size_t)j*Hn))[lane];
            const uint4 Wz = ((const uint4*)(Wih_h + (size_t)(Hn + j)*Hn))[lane];
            const uint4 Wn = ((const uint4*)(Wih_h + (size_t)(2*Hn + j)*Hn))[lane];
            const uint4 Ur = ((const uint4*)(Whh_h + (size_t)j*Hn))[lane];
            const uint4 Uz = ((const uint4*)(Whh_h + (size_t)(Hn + j)*Hn))[lane];
            const uint4 Un = ((const uint4*)(Whh_h + (size_t)(2*Hn + j)*Hn))[lane];
            const uint4 Xv = ((const uint4*)x_s)[lane];
            const uint4 Hv = ((const uint4*)hh_full)[lane];
            float gr = dot8h(Ur, Hv, dot8h(Wr, Xv, 0.0f));
            float gz = dot8h(Uz, Hv, dot8h(Wz, Xv, 0.0f));
            float an = dot8h(Wn, Xv, 0.0f);
            float cn = dot8h(Un, Hv, 0.0f);
            gr = wave_sum(gr); gz = wave_sum(gz);
            an = wave_sum(an); cn = wave_sum(cn);
            if (lane == 0) {
                const float r = fast_sigmoid(gr + bih[j]      + bhh[j]);
                const float z = fast_sigmoid(gz + bih[Hn+j]   + bhh[Hn+j]);
                const float n = fast_tanh(an + bih[2*Hn+j] + r*(cn + bhh[2*Hn+j]));
                const float hv = (1.0f - z)*n + z*h_full[j];
                h_full[j] = hv;              // in-place own slice (fp32 master)
                hn16_stage[jj] = f2h(hv);
            }
        }
        __syncthreads();

        // P6 (split by j): partial logits over owned j-slice (no bout here)
        for (int v = wid; v < Vn; v += 16) {
            const u32 w = *(const u32*)(Wout_h + (size_t)v*Hn + j0 + 2*lane);
            const u32 hh = ((u32*)hn16_stage)[lane];
            float acc = dot2acc(w, hh, 0.0f);
            acc = wave_sum(acc);
            if (lane == 0) plog_s[v] = acc;
        }
        __syncthreads();

        // exchange h (fp32 + fp16) and partial logits
        if (wid == 0) {
            if (lane < 50) {
                volatile float* pp = (volatile float*)(ws + OFF_PLOG) + ((size_t)b*4 + q)*100;
                pp[2*lane]   = plog_s[2*lane];
                pp[2*lane+1] = plog_s[2*lane+1];
            }
        } else if (wid == 1) {
            volatile float* hp = (volatile float*)(ws + OFF_HEX) + (size_t)b*Hn + j0;
            hp[2*lane]   = h_full[j0 + 2*lane];
            hp[2*lane+1] = h_full[j0 + 2*lane + 1];
        } else if (wid == 2) {
            ((volatile u32*)(ws + OFF_HHEX))[b*256 + q*64 + lane] = ((u32*)hn16_stage)[lane];
        }
        sib_barrier(cntB + b, tgtc);
        if (wid < 3) {
            const int qq = (q + 1 + wid) & 3;
            const volatile float* hp = (const volatile float*)(ws + OFF_HEX) + (size_t)b*Hn + qq*128;
            h_full[qq*128 + 2*lane]     = hp[2*lane];
            h_full[qq*128 + 2*lane + 1] = hp[2*lane+1];
            ((u32*)hh_full)[qq*64 + lane] = ((const volatile u32*)(ws + OFF_HHEX))[b*256 + qq*64 + lane];
        } else if (wid == 3) {
            ((u32*)hh_full)[q*64 + lane] = ((u32*)hn16_stage)[lane];
        } else if (wid == 4 && q == 0) {
            // P7: sum partials + log-softmax + store (sibling 0 only)
            float a0 = 0.f, a1 = 0.f;
            if (lane < 50) {
                a0 = plog_s[2*lane] + bout[2*lane];
                a1 = plog_s[2*lane+1] + bout[2*lane+1];
#pragma unroll
                for (int qq = 1; qq < 4; ++qq) {
                    const volatile float* pp = (const volatile float*)(ws + OFF_PLOG) + ((size_t)b*4 + qq)*100;
                    a0 += pp[2*lane];
                    a1 += pp[2*lane+1];
                }
            }
            const float l0 = (lane < 50) ? a0 : -3.0e38f;
            const float l1 = (lane < 50) ? a1 : -3.0e38f;
            const float mx = wave_max(fmaxf(l0, l1));
            const float e0 = (lane < 50) ? __expf(l0-mx) : 0.0f;
            const float e1 = (lane < 50) ? __expf(l1-mx) : 0.0f;
            const float lse = mx + __logf(wave_sum(e0 + e1));
            float* op = out + ((size_t)b*TSn + t)*Vn;
            if (lane < 50) { op[2*lane] = l0 - lse; op[2*lane+1] = l1 - lse; }
        }
        __syncthreads();
    }
}

extern "C" void kernel_launch(void* const* d_in, const int* in_sizes, int n_in,
                              void* d_out, int out_size, void* d_ws, size_t ws_size,
                              hipStream_t stream) {
    const float* enc   = (const float*)d_in[0];
    const float* Wemb  = (const float*)d_in[1];
    const float* Wcomb = (const float*)d_in[2];
    const float* bcomb = (const float*)d_in[3];
    const float* Wih   = (const float*)d_in[4];
    const float* Whh   = (const float*)d_in[5];
    const float* bih   = (const float*)d_in[6];
    const float* bhh   = (const float*)d_in[7];
    const float* Wout  = (const float*)d_in[8];
    const float* bout  = (const float*)d_in[9];
    const float* wvat  = (const float*)d_in[10];
    const float* bvat  = (const float*)d_in[11];
    const int*   tgt   = (const int*)d_in[12];
    float* out = (float*)d_out;
    char*  ws  = (char*)d_ws;

    conv_f16<<<1024, 256, 0, stream>>>(enc, Wemb, Wcomb, Wih, Whh, Wout, ws);

    void* args[] = { &bcomb, &bih, &bhh, &bout, &wvat, &bvat, &tgt, &out, &ws };
    hipLaunchCooperativeKernel((const void*)bahdanau_decoder,
                               dim3(256), dim3(1024), args, (size_t)(Sn*Hn*2), stream);
}